// Round 6
// baseline (326.822 us; speedup 1.0000x reference)
//
#include <hip/hip_runtime.h>
#include <hip/hip_bf16.h>

typedef __bf16 bf16;
typedef __attribute__((ext_vector_type(8))) __bf16 bf16x8;
typedef __attribute__((ext_vector_type(4))) __bf16 bf16x4;
typedef __attribute__((ext_vector_type(4))) float floatx4;

#define MFMA16(a, b, c) __builtin_amdgcn_mfma_f32_16x16x32_bf16((a), (b), (c), 0, 0, 0)

#define DIM 384
#define T1 3136   // 56*56
#define T2 784    // 28*28
#define T2P 832   // padded t for Vt columns
#define B_ 8
#define EPSV 1e-5f

__device__ __forceinline__ void gload_lds16(const bf16* g, bf16* l) {
  __builtin_amdgcn_global_load_lds(
      (const __attribute__((address_space(1))) void*)g,
      (__attribute__((address_space(3))) void*)l, 16, 0, 0);
}

// ---------------- fused depthwise convs + BN (q stride-1; k,v stride-2) + wcvt ------
__global__ void conv_fused_kernel(const float* __restrict__ x,
    const float* __restrict__ wqc, const float* __restrict__ gq, const float* __restrict__ bq,
    const float* __restrict__ mq, const float* __restrict__ vq,
    const float* __restrict__ wkc, const float* __restrict__ gk, const float* __restrict__ bk,
    const float* __restrict__ mk, const float* __restrict__ vk,
    const float* __restrict__ wvc, const float* __restrict__ gv, const float* __restrict__ bv,
    const float* __restrict__ mv, const float* __restrict__ vvv,
    bf16* __restrict__ qout, bf16* __restrict__ kout, bf16* __restrict__ vout,
    const float* __restrict__ w0, const float* __restrict__ w1,
    const float* __restrict__ w2, const float* __restrict__ w3,
    bf16* __restrict__ d0, bf16* __restrict__ d1,
    bf16* __restrict__ d2, bf16* __restrict__ d3) {
  int blk = blockIdx.x;
  int c = threadIdx.x;           // 0..383
  int gid = blk * DIM + c;
  if (gid < 147456) {            // folded weight conversion (first 384 blocks)
    d0[gid] = (bf16)w0[gid]; d1[gid] = (bf16)w1[gid];
    d2[gid] = (bf16)w2[gid]; d3[gid] = (bf16)w3[gid];
  }
  int xg = blk % 14;
  int y = (blk / 14) % 56;
  int b = blk / (14 * 56);
  int x0 = xg * 4;
  const float* xb = x + (size_t)b * T1 * DIM;
  float in[3][6];
#pragma unroll
  for (int r = 0; r < 3; ++r) {
    int yy = y + r - 1;
#pragma unroll
    for (int cc = 0; cc < 6; ++cc) {
      int xc = x0 + cc - 1;
      in[r][cc] = (yy >= 0 && yy < 56 && xc >= 0 && xc < 56)
                      ? xb[(yy * 56 + xc) * DIM + c] : 0.f;
    }
  }
  // q path
  {
    float wr[9];
#pragma unroll
    for (int i = 0; i < 9; ++i) wr[i] = wqc[c * 9 + i];
    float a = rsqrtf(vq[c] + EPSV) * gq[c];
    float bia = bq[c] - mq[c] * a;
#pragma unroll
    for (int p = 0; p < 4; ++p) {
      float s = 0.f;
#pragma unroll
      for (int r = 0; r < 3; ++r)
#pragma unroll
        for (int dx = 0; dx < 3; ++dx) s += in[r][p + dx] * wr[r * 3 + dx];
      qout[((size_t)b * T1 + y * 56 + x0 + p) * DIM + c] = (bf16)(s * a + bia);
    }
  }
  // kv path (block-uniform branch)
  if ((y & 1) == 0) {
    int y2 = y >> 1;
    float wk9[9], wv9[9];
#pragma unroll
    for (int i = 0; i < 9; ++i) { wk9[i] = wkc[c * 9 + i]; wv9[i] = wvc[c * 9 + i]; }
    float ak = rsqrtf(vk[c] + EPSV) * gk[c];
    float av = rsqrtf(vvv[c] + EPSV) * gv[c];
    float bik = bk[c] - mk[c] * ak;
    float biv = bv[c] - mv[c] * av;
#pragma unroll
    for (int p2 = 0; p2 < 2; ++p2) {
      float sk = 0.f, sv = 0.f;
#pragma unroll
      for (int r = 0; r < 3; ++r)
#pragma unroll
        for (int dx = 0; dx < 3; ++dx) {
          float xv = in[r][2 * p2 + dx];
          sk += xv * wk9[r * 3 + dx];
          sv += xv * wv9[r * 3 + dx];
        }
      size_t o = ((size_t)b * T2 + y2 * 28 + (x0 >> 1) + p2) * DIM + c;
      kout[o] = (bf16)(sk * ak + bik);
      vout[o] = (bf16)(sv * av + biv);
    }
  }
}

// ---------------- shared GEMM body: C[128,128] tile of A[M,384] @ W[384,384]^T ------
#define BK 32
__device__ __forceinline__
void gemm_body(const bf16* A, const bf16* Bw, void* out, const float* bias,
               int mode, float scale, int m0, int n0, bf16* Al, bf16* Bl) {
  int tid = threadIdx.x;
  int w = tid >> 6, lane = tid & 63;
  int wm = w >> 1, wn = w & 1;
  int l16 = lane & 15, quad = lane >> 4;
  floatx4 acc[4][4];
#pragma unroll
  for (int i = 0; i < 4; ++i)
#pragma unroll
    for (int j = 0; j < 4; ++j) acc[i][j] = (floatx4){0.f, 0.f, 0.f, 0.f};

  int srow = w * 32 + (lane >> 2);
  int scol = (lane & 3) * 8;
  const bf16* ag0 = &A[(size_t)(m0 + srow) * DIM + scol];
  const bf16* ag1 = ag0 + (size_t)16 * DIM;
  const bf16* bg0 = &Bw[(size_t)(n0 + srow) * DIM + scol];
  const bf16* bg1 = bg0 + (size_t)16 * DIM;
  bf16* la0 = &Al[(w * 32) * BK];
  bf16* la1 = &Al[(w * 32 + 16) * BK];
  bf16* lb0 = &Bl[(w * 32) * BK];
  bf16* lb1 = &Bl[(w * 32 + 16) * BK];

  for (int k0 = 0; k0 < DIM; k0 += BK) {
    __syncthreads();
    gload_lds16(ag0 + k0, la0);
    gload_lds16(ag1 + k0, la1);
    gload_lds16(bg0 + k0, lb0);
    gload_lds16(bg1 + k0, lb1);
    __syncthreads();
    bf16x8 af[4], bfr[4];
#pragma unroll
    for (int i = 0; i < 4; ++i) {
      af[i]  = *(const bf16x8*)&Al[(wm * 64 + i * 16 + l16) * BK + quad * 8];
      bfr[i] = *(const bf16x8*)&Bl[(wn * 64 + i * 16 + l16) * BK + quad * 8];
    }
#pragma unroll
    for (int i = 0; i < 4; ++i)
#pragma unroll
      for (int j = 0; j < 4; ++j)
        acc[i][j] = MFMA16(af[i], bfr[j], acc[i][j]);
  }
#pragma unroll
  for (int i = 0; i < 4; ++i) {
#pragma unroll
    for (int j = 0; j < 4; ++j) {
#pragma unroll
      for (int rr = 0; rr < 4; ++rr) {
        int row = m0 + wm * 64 + i * 16 + quad * 4 + rr;
        int col = n0 + wn * 64 + j * 16 + l16;
        float v = acc[i][j][rr];
        if (mode == 3) {
          ((float*)out)[(size_t)row * DIM + col] = v + bias[col];
        } else if (mode == 2) {
          int b = row / T2;
          int t = row - b * T2;
          ((bf16*)out)[((size_t)b * DIM + col) * T2P + t] = (bf16)v;
        } else {
          ((bf16*)out)[(size_t)row * DIM + col] = (bf16)(v * scale);
        }
      }
    }
  }
}

// Q (588) + K (147) + V (147) tiles in one launch; XCD-swizzled so the 3 n-tiles of
// one m-tile land on the same XCD (blockIdx%8 round-robin assumption; perf-only).
__global__ __launch_bounds__(256)
void qkv_gemm_kernel(const bf16* q_act, const bf16* k_act, const bf16* v_act,
                     const bf16* wqb, const bf16* wkb, const bf16* wvb,
                     bf16* Qp, bf16* Kp, bf16* Vtp, float qscale) {
  __shared__ bf16 Al[128 * BK];
  __shared__ bf16 Bl[128 * BK];
  int bx = blockIdx.x;
  int xp = bx & 7, j = bx >> 3;
  int t = (j / 3) * 24 + xp * 3 + (j % 3);
  if (t >= 882) return;
  const bf16 *A, *Bw; void* out; int mode, ti; float scale;
  if (t < 588)      { A = q_act; Bw = wqb; out = Qp;  mode = 1; scale = qscale; ti = t; }
  else if (t < 735) { A = k_act; Bw = wkb; out = Kp;  mode = 0; scale = 1.f; ti = t - 588; }
  else              { A = v_act; Bw = wvb; out = Vtp; mode = 2; scale = 1.f; ti = t - 735; }
  gemm_body(A, Bw, out, nullptr, mode, scale, (ti / 3) * 128, (ti % 3) * 128, Al, Bl);
}

__global__ __launch_bounds__(256)
void last_gemm_kernel(const bf16* A, const bf16* Bw, float* out, const float* bias) {
  __shared__ bf16 Al[128 * BK];
  __shared__ bf16 Bl[128 * BK];
  int bx = blockIdx.x;
  int xp = bx & 7, j = bx >> 3;
  int t = (j / 3) * 24 + xp * 3 + (j % 3);
  if (t >= 588) return;
  gemm_body(A, Bw, out, bias, 3, 1.f, (t / 3) * 128, (t % 3) * 128, Al, Bl);
}

// ---------------- flash attention, S^T/O^T form, no-max softmax -------------------
// Block = 4 waves, 128 q of one (b,h). XCD-swizzled grid: the 25 blocks sharing one
// (b,h)'s K/V co-locate on one XCD (K/V footprint 1.25 MB/XCD -> L2-resident).
// K staged once/block/iter via global_load_lds + chunk-XOR swizzle (2-barrier loop).
// V fragments read DIRECT from global (identical across waves; L1/L2-served) --
// removes 8 of 20 per-iter b128 LDS reads (LDS pipe was the measured floor).
// P round-trips wave-private LDS, stride 64 + XOR swizzle. LDS = 8+16 = 24 KB.
__global__ __launch_bounds__(256, 5)
void attn_kernel(const bf16* __restrict__ Qp, const bf16* __restrict__ Kp,
                 const bf16* __restrict__ Vt, bf16* __restrict__ Ob) {
  __shared__ bf16 Kl[64 * 64];            // [t][d], swizzled chunks (8 KB)
  __shared__ bf16 Pl[4][2][16 * 64];      // per-wave per-qtile [q][t], swizzled (16 KB)
  int bx = blockIdx.x;
  int xcd = bx & 7, j = bx >> 3;
  int g = xcd + 8 * (j / 25);             // (b,h) group 0..47, fixed per XCD
  int qblk = j % 25;
  int h = g % 6;
  int b = g / 6;
  int tid = threadIdx.x, w = tid >> 6, lane = tid & 63;
  int l16 = lane & 15, quad = lane >> 4;
  int q0w = qblk * 128 + w * 32;

  // Q fragments (B-operand layout: n = lane&15, k = quad*8+j); clamp OOB rows
  bf16x8 qf[2][2];
#pragma unroll
  for (int qt = 0; qt < 2; ++qt) {
    int qi = q0w + qt * 16 + l16;
    qi = qi < T1 ? qi : T1 - 1;
    const bf16* qp = &Qp[((size_t)b * T1 + qi) * DIM + h * 64];
    qf[qt][0] = *(const bf16x8*)&qp[quad * 8];
    qf[qt][1] = *(const bf16x8*)&qp[32 + quad * 8];
  }
  floatx4 oacc[2][4];
#pragma unroll
  for (int qt = 0; qt < 2; ++qt)
#pragma unroll
    for (int dt = 0; dt < 4; ++dt) oacc[qt][dt] = (floatx4){0.f, 0.f, 0.f, 0.f};
  float lsum[2] = {0.f, 0.f};

  // K staging: one instr = 8 rows x 128 B; lane -> (row=lane>>3, chunk=lane&7),
  // source chunk swizzled by row&7.
  int rsub = lane >> 3;
  int chnk = (lane & 7) ^ rsub;
  const bf16* kg0 = &Kp[((size_t)b * T2 + w * 16 + rsub) * DIM + h * 64 + chnk * 8];
  const bf16* kg1 = kg0 + (size_t)8 * DIM;
  bf16* kl0 = &Kl[(w * 16) * 64];
  bf16* kl1 = &Kl[(w * 16 + 8) * 64];

  // V direct-global fragment base (A-operand: m = l16 -> d row, k = quad*8+j -> t)
  const bf16* vbase = &Vt[((size_t)b * DIM + h * 64 + l16) * T2P + quad * 8];

  int key = l16 & 7;                      // fragment-read swizzle key

  for (int it = 0; it < 12; ++it) {
    __syncthreads();                      // prev iter's K reads done
    gload_lds16(kg0, kl0);
    gload_lds16(kg1, kl1);
    __syncthreads();                      // drains vmcnt: K tile ready
    // S^T = K Q^T per (mt, qt)
#pragma unroll
    for (int mt = 0; mt < 4; ++mt) {
      int krow = (mt * 16 + l16) * 64;
      bf16x8 kf0 = *(const bf16x8*)&Kl[krow + ((quad) ^ key) * 8];
      bf16x8 kf1 = *(const bf16x8*)&Kl[krow + ((quad + 4) ^ key) * 8];
      int pchunk = (((mt * 2 + (quad >> 1)) ^ key) << 3) + (quad & 1) * 4;
#pragma unroll
      for (int qt = 0; qt < 2; ++qt) {
        floatx4 z = (floatx4){0.f, 0.f, 0.f, 0.f};
        z = MFMA16(kf0, qf[qt][0], z);
        z = MFMA16(kf1, qf[qt][1], z);
        float p0 = __builtin_amdgcn_exp2f(z[0]);
        float p1 = __builtin_amdgcn_exp2f(z[1]);
        float p2 = __builtin_amdgcn_exp2f(z[2]);
        float p3 = __builtin_amdgcn_exp2f(z[3]);
        lsum[qt] += (p0 + p1) + (p2 + p3);
        bf16x4 pw = (bf16x4){(bf16)p0, (bf16)p1, (bf16)p2, (bf16)p3};
        *(bf16x4*)&Pl[w][qt][l16 * 64 + pchunk] = pw;
      }
    }
    // O^T += V^T P^T  (wave-private P; V fragments straight from global)
#pragma unroll
    for (int kt = 0; kt < 2; ++kt) {
      int rchunk = ((kt * 4 + quad) ^ key) << 3;
      bf16x8 pf0 = *(const bf16x8*)&Pl[w][0][l16 * 64 + rchunk];
      bf16x8 pf1 = *(const bf16x8*)&Pl[w][1][l16 * 64 + rchunk];
#pragma unroll
      for (int dt = 0; dt < 4; ++dt) {
        bf16x8 vf = *(const bf16x8*)(vbase + (size_t)(dt * 16) * T2P + kt * 32);
        oacc[0][dt] = MFMA16(vf, pf0, oacc[0][dt]);
        oacc[1][dt] = MFMA16(vf, pf1, oacc[1][dt]);
      }
    }
    kg0 += (size_t)64 * DIM; kg1 += (size_t)64 * DIM;
    vbase += 64;
  }
  // tail: t 768..783 (direct loads; mt0 valid, zero mt1, kt=0 PV)
  {
    const bf16* kptr = &Kp[((size_t)b * T2 + 768 + l16) * DIM + h * 64 + quad * 8];
    bf16x8 kf0 = *(const bf16x8*)(kptr);
    bf16x8 kf1 = *(const bf16x8*)(kptr + 32);
    bf16x4 zz = (bf16x4){(bf16)0.f, (bf16)0.f, (bf16)0.f, (bf16)0.f};
    int pc0 = ((((quad >> 1)) ^ key) << 3) + (quad & 1) * 4;       // mt=0 chunks
    int pc1 = (((2 + (quad >> 1)) ^ key) << 3) + (quad & 1) * 4;   // mt=1 chunks
#pragma unroll
    for (int qt = 0; qt < 2; ++qt) {
      floatx4 z = (floatx4){0.f, 0.f, 0.f, 0.f};
      z = MFMA16(kf0, qf[qt][0], z);
      z = MFMA16(kf1, qf[qt][1], z);
      float p0 = __builtin_amdgcn_exp2f(z[0]);
      float p1 = __builtin_amdgcn_exp2f(z[1]);
      float p2 = __builtin_amdgcn_exp2f(z[2]);
      float p3 = __builtin_amdgcn_exp2f(z[3]);
      lsum[qt] += (p0 + p1) + (p2 + p3);
      bf16x4 pw = (bf16x4){(bf16)p0, (bf16)p1, (bf16)p2, (bf16)p3};
      *(bf16x4*)&Pl[w][qt][l16 * 64 + pc0] = pw;
      *(bf16x4*)&Pl[w][qt][l16 * 64 + pc1] = zz;
    }
    int rchunk = (quad ^ key) << 3;
    bf16x8 pf0 = *(const bf16x8*)&Pl[w][0][l16 * 64 + rchunk];
    bf16x8 pf1 = *(const bf16x8*)&Pl[w][1][l16 * 64 + rchunk];
#pragma unroll
    for (int dt = 0; dt < 4; ++dt) {
      bf16x8 vf = *(const bf16x8*)(vbase + (size_t)(dt * 16) * T2P);
      oacc[0][dt] = MFMA16(vf, pf0, oacc[0][dt]);
      oacc[1][dt] = MFMA16(vf, pf1, oacc[1][dt]);
    }
  }
  // epilogue: reduce l across quads, scale, pack 4 bf16 -> 8B stores
#pragma unroll
  for (int qt = 0; qt < 2; ++qt) {
    float l = lsum[qt];
    l += __shfl_xor(l, 16);
    l += __shfl_xor(l, 32);
    float inv = 1.f / l;
    int qg = q0w + qt * 16 + l16;
    if (qg < T1) {
      bf16* op = &Ob[((size_t)b * T1 + qg) * DIM + h * 64];
#pragma unroll
      for (int dt = 0; dt < 4; ++dt) {
        floatx4 o = oacc[qt][dt];
        bf16x4 ov = (bf16x4){(bf16)(o[0] * inv), (bf16)(o[1] * inv),
                             (bf16)(o[2] * inv), (bf16)(o[3] * inv)};
        *(bf16x4*)&op[dt * 16 + quad * 4] = ov;
      }
    }
  }
}

// ---------------- launch ----------------
extern "C" void kernel_launch(void* const* d_in, const int* in_sizes, int n_in,
                              void* d_out, int out_size, void* d_ws, size_t ws_size,
                              hipStream_t stream) {
  (void)in_sizes; (void)n_in; (void)out_size; (void)ws_size;
  const float* x      = (const float*)d_in[0];
  const float* conv_q = (const float*)d_in[3];
  const float* bnq_s  = (const float*)d_in[4];
  const float* bnq_b  = (const float*)d_in[5];
  const float* bnq_m  = (const float*)d_in[6];
  const float* bnq_v  = (const float*)d_in[7];
  const float* conv_k = (const float*)d_in[8];
  const float* bnk_s  = (const float*)d_in[9];
  const float* bnk_b  = (const float*)d_in[10];
  const float* bnk_m  = (const float*)d_in[11];
  const float* bnk_v  = (const float*)d_in[12];
  const float* conv_v = (const float*)d_in[13];
  const float* bnv_s  = (const float*)d_in[14];
  const float* bnv_b  = (const float*)d_in[15];
  const float* bnv_m  = (const float*)d_in[16];
  const float* bnv_v  = (const float*)d_in[17];
  const float* wq     = (const float*)d_in[18];
  const float* wk     = (const float*)d_in[19];
  const float* wv     = (const float*)d_in[20];
  const float* wl     = (const float*)d_in[21];
  const float* b_last = (const float*)d_in[22];

  char* ws = (char*)d_ws;
  bf16* q_act = (bf16*)(ws + 0);               // 19267584; reused as attention output
  bf16* k_act = (bf16*)(ws + 19267584);        // 4816896
  bf16* v_act = (bf16*)(ws + 24084480);        // 4816896
  bf16* Qp    = (bf16*)(ws + 28901376);        // 19267584 (pre-scaled by SCALE*log2e)
  bf16* Kp    = (bf16*)(ws + 48168960);        // 4816896
  bf16* Vtp   = (bf16*)(ws + 52985856);        // 8*384*832*2 = 5111808  [B][384][T2P]
  bf16* wqb   = (bf16*)(ws + 58097664);        // 294912 each, x4
  bf16* wkb   = wqb + 147456;
  bf16* wvb   = wkb + 147456;
  bf16* wlb   = wvb + 147456;

  const float QSCALE = 0.05103103630798288f * 1.4426950408889634f;  // 384^-0.5 * log2e

  conv_fused_kernel<<<B_ * 56 * 14, DIM, 0, stream>>>(
      x,
      conv_q, bnq_s, bnq_b, bnq_m, bnq_v,
      conv_k, bnk_s, bnk_b, bnk_m, bnk_v,
      conv_v, bnv_s, bnv_b, bnv_m, bnv_v,
      q_act, k_act, v_act,
      wq, wk, wv, wl, wqb, wkb, wvb, wlb);

  qkv_gemm_kernel<<<888, 256, 0, stream>>>(q_act, k_act, v_act, wqb, wkb, wvb,
                                           Qp, Kp, Vtp, QSCALE);

  attn_kernel<<<25 * 6 * B_, 256, 0, stream>>>(Qp, Kp, Vtp, q_act);

  last_gemm_kernel<<<600, 256, 0, stream>>>(q_act, wlb, (float*)d_out, b_last);
}

// Round 7
// 259.456 us; speedup vs baseline: 1.2596x; 1.2596x over previous
//
#include <hip/hip_runtime.h>
#include <hip/hip_bf16.h>

typedef __bf16 bf16;
typedef __attribute__((ext_vector_type(8))) __bf16 bf16x8;
typedef __attribute__((ext_vector_type(4))) __bf16 bf16x4;
typedef __attribute__((ext_vector_type(4))) float floatx4;

#define MFMA16(a, b, c) __builtin_amdgcn_mfma_f32_16x16x32_bf16((a), (b), (c), 0, 0, 0)

#define DIM 384
#define T1 3136   // 56*56
#define T2 784    // 28*28
#define T2P 832   // padded t for Vt columns
#define B_ 8
#define EPSV 1e-5f

__device__ __forceinline__ void gload_lds16(const bf16* g, bf16* l) {
  __builtin_amdgcn_global_load_lds(
      (const __attribute__((address_space(1))) void*)g,
      (__attribute__((address_space(3))) void*)l, 16, 0, 0);
}

// ---------------- fused depthwise convs + BN (q stride-1; k,v stride-2) + wcvt ------
__global__ void conv_fused_kernel(const float* __restrict__ x,
    const float* __restrict__ wqc, const float* __restrict__ gq, const float* __restrict__ bq,
    const float* __restrict__ mq, const float* __restrict__ vq,
    const float* __restrict__ wkc, const float* __restrict__ gk, const float* __restrict__ bk,
    const float* __restrict__ mk, const float* __restrict__ vk,
    const float* __restrict__ wvc, const float* __restrict__ gv, const float* __restrict__ bv,
    const float* __restrict__ mv, const float* __restrict__ vvv,
    bf16* __restrict__ qout, bf16* __restrict__ kout, bf16* __restrict__ vout,
    const float* __restrict__ w0, const float* __restrict__ w1,
    const float* __restrict__ w2, const float* __restrict__ w3,
    bf16* __restrict__ d0, bf16* __restrict__ d1,
    bf16* __restrict__ d2, bf16* __restrict__ d3) {
  int blk = blockIdx.x;
  int c = threadIdx.x;           // 0..383
  int gid = blk * DIM + c;
  if (gid < 147456) {            // folded weight conversion (first 384 blocks)
    d0[gid] = (bf16)w0[gid]; d1[gid] = (bf16)w1[gid];
    d2[gid] = (bf16)w2[gid]; d3[gid] = (bf16)w3[gid];
  }
  int xg = blk % 14;
  int y = (blk / 14) % 56;
  int b = blk / (14 * 56);
  int x0 = xg * 4;
  const float* xb = x + (size_t)b * T1 * DIM;
  float in[3][6];
#pragma unroll
  for (int r = 0; r < 3; ++r) {
    int yy = y + r - 1;
#pragma unroll
    for (int cc = 0; cc < 6; ++cc) {
      int xc = x0 + cc - 1;
      in[r][cc] = (yy >= 0 && yy < 56 && xc >= 0 && xc < 56)
                      ? xb[(yy * 56 + xc) * DIM + c] : 0.f;
    }
  }
  // q path
  {
    float wr[9];
#pragma unroll
    for (int i = 0; i < 9; ++i) wr[i] = wqc[c * 9 + i];
    float a = rsqrtf(vq[c] + EPSV) * gq[c];
    float bia = bq[c] - mq[c] * a;
#pragma unroll
    for (int p = 0; p < 4; ++p) {
      float s = 0.f;
#pragma unroll
      for (int r = 0; r < 3; ++r)
#pragma unroll
        for (int dx = 0; dx < 3; ++dx) s += in[r][p + dx] * wr[r * 3 + dx];
      qout[((size_t)b * T1 + y * 56 + x0 + p) * DIM + c] = (bf16)(s * a + bia);
    }
  }
  // kv path (block-uniform branch)
  if ((y & 1) == 0) {
    int y2 = y >> 1;
    float wk9[9], wv9[9];
#pragma unroll
    for (int i = 0; i < 9; ++i) { wk9[i] = wkc[c * 9 + i]; wv9[i] = wvc[c * 9 + i]; }
    float ak = rsqrtf(vk[c] + EPSV) * gk[c];
    float av = rsqrtf(vvv[c] + EPSV) * gv[c];
    float bik = bk[c] - mk[c] * ak;
    float biv = bv[c] - mv[c] * av;
#pragma unroll
    for (int p2 = 0; p2 < 2; ++p2) {
      float sk = 0.f, sv = 0.f;
#pragma unroll
      for (int r = 0; r < 3; ++r)
#pragma unroll
        for (int dx = 0; dx < 3; ++dx) {
          float xv = in[r][2 * p2 + dx];
          sk += xv * wk9[r * 3 + dx];
          sv += xv * wv9[r * 3 + dx];
        }
      size_t o = ((size_t)b * T2 + y2 * 28 + (x0 >> 1) + p2) * DIM + c;
      kout[o] = (bf16)(sk * ak + bik);
      vout[o] = (bf16)(sv * av + biv);
    }
  }
}

// ---------------- shared GEMM body: C[128,128] tile of A[M,384] @ W[384,384]^T ------
#define BK 32
__device__ __forceinline__
void gemm_body(const bf16* A, const bf16* Bw, void* out, const float* bias,
               int mode, float scale, int m0, int n0, bf16* Al, bf16* Bl) {
  int tid = threadIdx.x;
  int w = tid >> 6, lane = tid & 63;
  int wm = w >> 1, wn = w & 1;
  int l16 = lane & 15, quad = lane >> 4;
  floatx4 acc[4][4];
#pragma unroll
  for (int i = 0; i < 4; ++i)
#pragma unroll
    for (int j = 0; j < 4; ++j) acc[i][j] = (floatx4){0.f, 0.f, 0.f, 0.f};

  int srow = w * 32 + (lane >> 2);
  int scol = (lane & 3) * 8;
  const bf16* ag0 = &A[(size_t)(m0 + srow) * DIM + scol];
  const bf16* ag1 = ag0 + (size_t)16 * DIM;
  const bf16* bg0 = &Bw[(size_t)(n0 + srow) * DIM + scol];
  const bf16* bg1 = bg0 + (size_t)16 * DIM;
  bf16* la0 = &Al[(w * 32) * BK];
  bf16* la1 = &Al[(w * 32 + 16) * BK];
  bf16* lb0 = &Bl[(w * 32) * BK];
  bf16* lb1 = &Bl[(w * 32 + 16) * BK];

  for (int k0 = 0; k0 < DIM; k0 += BK) {
    __syncthreads();
    gload_lds16(ag0 + k0, la0);
    gload_lds16(ag1 + k0, la1);
    gload_lds16(bg0 + k0, lb0);
    gload_lds16(bg1 + k0, lb1);
    __syncthreads();
    bf16x8 af[4], bfr[4];
#pragma unroll
    for (int i = 0; i < 4; ++i) {
      af[i]  = *(const bf16x8*)&Al[(wm * 64 + i * 16 + l16) * BK + quad * 8];
      bfr[i] = *(const bf16x8*)&Bl[(wn * 64 + i * 16 + l16) * BK + quad * 8];
    }
#pragma unroll
    for (int i = 0; i < 4; ++i)
#pragma unroll
      for (int j = 0; j < 4; ++j)
        acc[i][j] = MFMA16(af[i], bfr[j], acc[i][j]);
  }
#pragma unroll
  for (int i = 0; i < 4; ++i) {
#pragma unroll
    for (int j = 0; j < 4; ++j) {
#pragma unroll
      for (int rr = 0; rr < 4; ++rr) {
        int row = m0 + wm * 64 + i * 16 + quad * 4 + rr;
        int col = n0 + wn * 64 + j * 16 + l16;
        float v = acc[i][j][rr];
        if (mode == 3) {
          ((float*)out)[(size_t)row * DIM + col] = v + bias[col];
        } else if (mode == 2) {
          int b = row / T2;
          int t = row - b * T2;
          ((bf16*)out)[((size_t)b * DIM + col) * T2P + t] = (bf16)v;
        } else {
          ((bf16*)out)[(size_t)row * DIM + col] = (bf16)(v * scale);
        }
      }
    }
  }
}

// Q (588) + K (147) + V (147) tiles in one launch; XCD-swizzled so the 3 n-tiles of
// one m-tile land on the same XCD (blockIdx%8 round-robin assumption; perf-only).
__global__ __launch_bounds__(256)
void qkv_gemm_kernel(const bf16* q_act, const bf16* k_act, const bf16* v_act,
                     const bf16* wqb, const bf16* wkb, const bf16* wvb,
                     bf16* Qp, bf16* Kp, bf16* Vtp, float qscale) {
  __shared__ bf16 Al[128 * BK];
  __shared__ bf16 Bl[128 * BK];
  int bx = blockIdx.x;
  int xp = bx & 7, j = bx >> 3;
  int t = (j / 3) * 24 + xp * 3 + (j % 3);
  if (t >= 882) return;
  const bf16 *A, *Bw; void* out; int mode, ti; float scale;
  if (t < 588)      { A = q_act; Bw = wqb; out = Qp;  mode = 1; scale = qscale; ti = t; }
  else if (t < 735) { A = k_act; Bw = wkb; out = Kp;  mode = 0; scale = 1.f; ti = t - 588; }
  else              { A = v_act; Bw = wvb; out = Vtp; mode = 2; scale = 1.f; ti = t - 735; }
  gemm_body(A, Bw, out, nullptr, mode, scale, (ti / 3) * 128, (ti % 3) * 128, Al, Bl);
}

__global__ __launch_bounds__(256)
void last_gemm_kernel(const bf16* A, const bf16* Bw, float* out, const float* bias) {
  __shared__ bf16 Al[128 * BK];
  __shared__ bf16 Bl[128 * BK];
  int bx = blockIdx.x;
  int xp = bx & 7, j = bx >> 3;
  int t = (j / 3) * 24 + xp * 3 + (j % 3);
  if (t >= 588) return;
  gemm_body(A, Bw, out, bias, 3, 1.f, (t / 3) * 128, (t % 3) * 128, Al, Bl);
}

// ---------------- flash attention, S^T/O^T form, no-max softmax -------------------
// R4 dataflow (proven 54 us): K AND V staged once/block/iter via global_load_lds with
// chunk-XOR swizzle, 2-barrier loop; P wave-private LDS (no barrier), stride-64 with
// XOR swizzle (R5) -> LDS exactly 32 KB; XCD group swizzle (R6): the 25 blocks of one
// (b,h) share an XCD so its K/V (1.25 MB) stays L2-resident.
__global__ __launch_bounds__(256, 4)
void attn_kernel(const bf16* __restrict__ Qp, const bf16* __restrict__ Kp,
                 const bf16* __restrict__ Vt, bf16* __restrict__ Ob) {
  __shared__ bf16 Kl[64 * 64];            // [t][d], swizzled chunks (8 KB)
  __shared__ bf16 Vl[64 * 64];            // [d][t], swizzled chunks (8 KB)
  __shared__ bf16 Pl[4][2][16 * 64];      // per-wave per-qtile [q][t], swizzled (16 KB)
  int bx = blockIdx.x;
  int xcd = bx & 7, j = bx >> 3;
  int g = xcd + 8 * (j / 25);             // (b,h) group 0..47, fixed per XCD
  int qblk = j % 25;
  int h = g % 6;
  int b = g / 6;
  int tid = threadIdx.x, w = tid >> 6, lane = tid & 63;
  int l16 = lane & 15, quad = lane >> 4;
  int q0w = qblk * 128 + w * 32;

  // Q fragments (B-operand layout: n = lane&15, k = quad*8+j); clamp OOB rows
  bf16x8 qf[2][2];
#pragma unroll
  for (int qt = 0; qt < 2; ++qt) {
    int qi = q0w + qt * 16 + l16;
    qi = qi < T1 ? qi : T1 - 1;
    const bf16* qp = &Qp[((size_t)b * T1 + qi) * DIM + h * 64];
    qf[qt][0] = *(const bf16x8*)&qp[quad * 8];
    qf[qt][1] = *(const bf16x8*)&qp[32 + quad * 8];
  }
  floatx4 oacc[2][4];
#pragma unroll
  for (int qt = 0; qt < 2; ++qt)
#pragma unroll
    for (int dt = 0; dt < 4; ++dt) oacc[qt][dt] = (floatx4){0.f, 0.f, 0.f, 0.f};
  float lsum[2] = {0.f, 0.f};

  // staging: one instr = 8 rows x 128 B; lane -> (row=lane>>3, chunk=lane&7),
  // source chunk swizzled by row&7.
  int rsub = lane >> 3;
  int chnk = (lane & 7) ^ rsub;
  const bf16* kg0 = &Kp[((size_t)b * T2 + w * 16 + rsub) * DIM + h * 64 + chnk * 8];
  const bf16* kg1 = kg0 + (size_t)8 * DIM;
  const bf16* vg0 = &Vt[((size_t)b * DIM + h * 64 + w * 16 + rsub) * T2P + chnk * 8];
  const bf16* vg1 = vg0 + (size_t)8 * T2P;
  bf16* kl0 = &Kl[(w * 16) * 64];
  bf16* kl1 = &Kl[(w * 16 + 8) * 64];
  bf16* vl0 = &Vl[(w * 16) * 64];
  bf16* vl1 = &Vl[(w * 16 + 8) * 64];

  int key = l16 & 7;                      // fragment-read swizzle key

  for (int it = 0; it < 12; ++it) {
    __syncthreads();                      // prev iter's tile reads done
    gload_lds16(kg0, kl0);
    gload_lds16(kg1, kl1);
    gload_lds16(vg0, vl0);
    gload_lds16(vg1, vl1);
    __syncthreads();                      // drains vmcnt: tiles ready
    // S^T = K Q^T per (mt, qt)
#pragma unroll
    for (int mt = 0; mt < 4; ++mt) {
      int krow = (mt * 16 + l16) * 64;
      bf16x8 kf0 = *(const bf16x8*)&Kl[krow + ((quad) ^ key) * 8];
      bf16x8 kf1 = *(const bf16x8*)&Kl[krow + ((quad + 4) ^ key) * 8];
      int pchunk = (((mt * 2 + (quad >> 1)) ^ key) << 3) + (quad & 1) * 4;
#pragma unroll
      for (int qt = 0; qt < 2; ++qt) {
        floatx4 z = (floatx4){0.f, 0.f, 0.f, 0.f};
        z = MFMA16(kf0, qf[qt][0], z);
        z = MFMA16(kf1, qf[qt][1], z);
        float p0 = __builtin_amdgcn_exp2f(z[0]);
        float p1 = __builtin_amdgcn_exp2f(z[1]);
        float p2 = __builtin_amdgcn_exp2f(z[2]);
        float p3 = __builtin_amdgcn_exp2f(z[3]);
        lsum[qt] += (p0 + p1) + (p2 + p3);
        bf16x4 pw = (bf16x4){(bf16)p0, (bf16)p1, (bf16)p2, (bf16)p3};
        *(bf16x4*)&Pl[w][qt][l16 * 64 + pchunk] = pw;
      }
    }
    // O^T += V^T P^T  (wave-private P: same-wave DS ordering, no barrier)
#pragma unroll
    for (int kt = 0; kt < 2; ++kt) {
      int rchunk = ((kt * 4 + quad) ^ key) << 3;
      bf16x8 pf0 = *(const bf16x8*)&Pl[w][0][l16 * 64 + rchunk];
      bf16x8 pf1 = *(const bf16x8*)&Pl[w][1][l16 * 64 + rchunk];
#pragma unroll
      for (int dt = 0; dt < 4; ++dt) {
        bf16x8 vf = *(const bf16x8*)&Vl[(dt * 16 + l16) * 64 + ((kt * 4 + quad) ^ key) * 8];
        oacc[0][dt] = MFMA16(vf, pf0, oacc[0][dt]);
        oacc[1][dt] = MFMA16(vf, pf1, oacc[1][dt]);
      }
    }
    kg0 += (size_t)64 * DIM; kg1 += (size_t)64 * DIM;
    vg0 += 64; vg1 += 64;
  }
  // tail: t 768..783 (direct global fragment loads; mt0 valid, zero mt1, kt=0 PV)
  {
    const bf16* kptr = &Kp[((size_t)b * T2 + 768 + l16) * DIM + h * 64 + quad * 8];
    const bf16* vptr = &Vt[((size_t)b * DIM + h * 64 + l16) * T2P + 768 + quad * 8];
    bf16x8 kf0 = *(const bf16x8*)(kptr);
    bf16x8 kf1 = *(const bf16x8*)(kptr + 32);
    bf16x4 zz = (bf16x4){(bf16)0.f, (bf16)0.f, (bf16)0.f, (bf16)0.f};
    int pc0 = ((((quad >> 1)) ^ key) << 3) + (quad & 1) * 4;       // mt=0 chunks
    int pc1 = (((2 + (quad >> 1)) ^ key) << 3) + (quad & 1) * 4;   // mt=1 chunks
#pragma unroll
    for (int qt = 0; qt < 2; ++qt) {
      floatx4 z = (floatx4){0.f, 0.f, 0.f, 0.f};
      z = MFMA16(kf0, qf[qt][0], z);
      z = MFMA16(kf1, qf[qt][1], z);
      float p0 = __builtin_amdgcn_exp2f(z[0]);
      float p1 = __builtin_amdgcn_exp2f(z[1]);
      float p2 = __builtin_amdgcn_exp2f(z[2]);
      float p3 = __builtin_amdgcn_exp2f(z[3]);
      lsum[qt] += (p0 + p1) + (p2 + p3);
      bf16x4 pw = (bf16x4){(bf16)p0, (bf16)p1, (bf16)p2, (bf16)p3};
      *(bf16x4*)&Pl[w][qt][l16 * 64 + pc0] = pw;
      *(bf16x4*)&Pl[w][qt][l16 * 64 + pc1] = zz;
    }
    int rchunk = (quad ^ key) << 3;
    bf16x8 pf0 = *(const bf16x8*)&Pl[w][0][l16 * 64 + rchunk];
    bf16x8 pf1 = *(const bf16x8*)&Pl[w][1][l16 * 64 + rchunk];
#pragma unroll
    for (int dt = 0; dt < 4; ++dt) {
      bf16x8 vf = *(const bf16x8*)(vptr + (size_t)(dt * 16) * T2P);
      oacc[0][dt] = MFMA16(vf, pf0, oacc[0][dt]);
      oacc[1][dt] = MFMA16(vf, pf1, oacc[1][dt]);
    }
  }
  // epilogue: reduce l across quads, scale, pack 4 bf16 -> 8B stores
#pragma unroll
  for (int qt = 0; qt < 2; ++qt) {
    float l = lsum[qt];
    l += __shfl_xor(l, 16);
    l += __shfl_xor(l, 32);
    float inv = 1.f / l;
    int qg = q0w + qt * 16 + l16;
    if (qg < T1) {
      bf16* op = &Ob[((size_t)b * T1 + qg) * DIM + h * 64];
#pragma unroll
      for (int dt = 0; dt < 4; ++dt) {
        floatx4 o = oacc[qt][dt];
        bf16x4 ov = (bf16x4){(bf16)(o[0] * inv), (bf16)(o[1] * inv),
                             (bf16)(o[2] * inv), (bf16)(o[3] * inv)};
        *(bf16x4*)&op[dt * 16 + quad * 4] = ov;
      }
    }
  }
}

// ---------------- launch ----------------
extern "C" void kernel_launch(void* const* d_in, const int* in_sizes, int n_in,
                              void* d_out, int out_size, void* d_ws, size_t ws_size,
                              hipStream_t stream) {
  (void)in_sizes; (void)n_in; (void)out_size; (void)ws_size;
  const float* x      = (const float*)d_in[0];
  const float* conv_q = (const float*)d_in[3];
  const float* bnq_s  = (const float*)d_in[4];
  const float* bnq_b  = (const float*)d_in[5];
  const float* bnq_m  = (const float*)d_in[6];
  const float* bnq_v  = (const float*)d_in[7];
  const float* conv_k = (const float*)d_in[8];
  const float* bnk_s  = (const float*)d_in[9];
  const float* bnk_b  = (const float*)d_in[10];
  const float* bnk_m  = (const float*)d_in[11];
  const float* bnk_v  = (const float*)d_in[12];
  const float* conv_v = (const float*)d_in[13];
  const float* bnv_s  = (const float*)d_in[14];
  const float* bnv_b  = (const float*)d_in[15];
  const float* bnv_m  = (const float*)d_in[16];
  const float* bnv_v  = (const float*)d_in[17];
  const float* wq     = (const float*)d_in[18];
  const float* wk     = (const float*)d_in[19];
  const float* wv     = (const float*)d_in[20];
  const float* wl     = (const float*)d_in[21];
  const float* b_last = (const float*)d_in[22];

  char* ws = (char*)d_ws;
  bf16* q_act = (bf16*)(ws + 0);               // 19267584; reused as attention output
  bf16* k_act = (bf16*)(ws + 19267584);        // 4816896
  bf16* v_act = (bf16*)(ws + 24084480);        // 4816896
  bf16* Qp    = (bf16*)(ws + 28901376);        // 19267584 (pre-scaled by SCALE*log2e)
  bf16* Kp    = (bf16*)(ws + 48168960);        // 4816896
  bf16* Vtp   = (bf16*)(ws + 52985856);        // 8*384*832*2 = 5111808  [B][384][T2P]
  bf16* wqb   = (bf16*)(ws + 58097664);        // 294912 each, x4
  bf16* wkb   = wqb + 147456;
  bf16* wvb   = wkb + 147456;
  bf16* wlb   = wvb + 147456;

  const float QSCALE = 0.05103103630798288f * 1.4426950408889634f;  // 384^-0.5 * log2e

  conv_fused_kernel<<<B_ * 56 * 14, DIM, 0, stream>>>(
      x,
      conv_q, bnq_s, bnq_b, bnq_m, bnq_v,
      conv_k, bnk_s, bnk_b, bnk_m, bnk_v,
      conv_v, bnv_s, bnv_b, bnv_m, bnv_v,
      q_act, k_act, v_act,
      wq, wk, wv, wl, wqb, wkb, wvb, wlb);

  qkv_gemm_kernel<<<888, 256, 0, stream>>>(q_act, k_act, v_act, wqb, wkb, wvb,
                                           Qp, Kp, Vtp, QSCALE);

  attn_kernel<<<25 * 6 * B_, 256, 0, stream>>>(Qp, Kp, Vtp, q_act);

  last_gemm_kernel<<<600, 256, 0, stream>>>(q_act, wlb, (float*)d_out, b_last);
}